// Round 10
// baseline (228.228 us; speedup 1.0000x reference)
//
#include <hip/hip_runtime.h>

#define NEGV (-10000000000.0f)

typedef unsigned short u16;
typedef _Float16 __attribute__((ext_vector_type(8))) f16x8;
typedef _Float16 __attribute__((ext_vector_type(4))) f16x4;
typedef __attribute__((ext_vector_type(4))) float f32x4;

__device__ __forceinline__ u16 f2fh(float f) {
  _Float16 h = (_Float16)f;
  return __builtin_bit_cast(u16, h);
}

__device__ __forceinline__ void gload16(const u16* g, u16* l) {
  __builtin_amdgcn_global_load_lds(
      (const __attribute__((address_space(1))) void*)g,
      (__attribute__((address_space(3))) void*)l, 16, 0, 0);
}

__device__ __forceinline__ f16x8 cvt8(float4 x, float4 y) {
  f16x8 o;
  o[0] = (_Float16)x.x; o[1] = (_Float16)x.y;
  o[2] = (_Float16)x.z; o[3] = (_Float16)x.w;
  o[4] = (_Float16)y.x; o[5] = (_Float16)y.y;
  o[6] = (_Float16)y.z; o[7] = (_Float16)y.w;
  return o;
}

// ---------------------------------------------------------------------------
// grid barrier v2. Arrival: 8 leaf counters (separate cachelines, 64 RMWs
// each, parallel across lines) -> 8-way root. Spin: device-scope atomic LOAD
// of the generation word (read-only -> no cross-XCD cacheline bouncing; served
// by the coherent memory-side L3). Separate counter sets per barrier instance
// (no in-kernel reset). bar[] zeroed by hipMemsetAsync each launch.
// ---------------------------------------------------------------------------
__device__ __forceinline__ void gridbar(unsigned* bar, int inst, int bid) {
  __syncthreads();
  if (threadIdx.x == 0) {
    __threadfence();                                   // release phase writes
    unsigned g = __hip_atomic_load(bar, __ATOMIC_ACQUIRE,
                                   __HIP_MEMORY_SCOPE_AGENT);
    unsigned* root = bar + 32 + (size_t)inst * 512;
    unsigned* leaf = bar + 64 + (size_t)inst * 512 + (size_t)(bid >> 6) * 32;
    bool open = false;
    if (atomicAdd(leaf, 1u) == 63u)
      if (atomicAdd(root, 1u) == 7u) open = true;
    if (open) {
      __threadfence();
      __hip_atomic_store(bar, g + 1u, __ATOMIC_RELEASE,
                         __HIP_MEMORY_SCOPE_AGENT);
    } else {
      while (__hip_atomic_load(bar, __ATOMIC_ACQUIRE,
                               __HIP_MEMORY_SCOPE_AGENT) == g)
        __builtin_amdgcn_s_sleep(1);
    }
    __threadfence();                                   // acquire
  }
  __syncthreads();
}

// ---------------------------------------------------------------------------
// shared MFMA inner step: 64x64 tile in sA/sB ([row][64 fp16] = 128B rows,
// oct-granular XOR swizzle byte ^= (row&7)<<4), 4 waves (2x2), 2x2 fragments.
// ---------------------------------------------------------------------------
__device__ __forceinline__ void mfma_tile(const u16* sA, const u16* sB,
                                          int l, int wr, int wc,
                                          f32x4 (*acc)[2]) {
#pragma unroll
  for (int ks = 0; ks < 2; ks++) {
    f16x8 af[2], bfr[2];
#pragma unroll
    for (int f = 0; f < 2; f++) {
      int cb = (ks * 32 + ((l >> 4) << 3)) << 1;
      int row = wr * 32 + f * 16 + (l & 15);
      af[f] = *(const f16x8*)((const char*)sA + row * 128 + (cb ^ ((row & 7) << 4)));
      int col = wc * 32 + f * 16 + (l & 15);
      bfr[f] = *(const f16x8*)((const char*)sB + col * 128 + (cb ^ ((col & 7) << 4)));
    }
#pragma unroll
    for (int fm = 0; fm < 2; fm++)
#pragma unroll
      for (int fn = 0; fn < 2; fn++)
        acc[fm][fn] = __builtin_amdgcn_mfma_f32_16x16x32_f16(
            af[fm], bfr[fn], acc[fm][fn], 0, 0, 0);
  }
}

// ---------------------------------------------------------------------------
// phase 1: proj. f32 inputs, in-register fp16 convert into swizzled LDS.
// units 0..63: qpE = exp(2(query·Wq^T + b)); 64..319: kpE = exp(2(Wk·kv^T)).
// ---------------------------------------------------------------------------
__device__ void proj_phase(
    int id, int t,
    const float* __restrict__ query, const float* __restrict__ kv,
    const float* __restrict__ W, const float* __restrict__ bias,
    float* __restrict__ qpE, float* __restrict__ kpE,
    u16* sA, u16* sB)
{
  const float *A, *B; float* C;
  int lda, ldb, ldc, bm, bn;
  const float* bp = nullptr;
  if (id < 64) {
    A = query; lda = 512; B = W; ldb = 1024;
    C = qpE; ldc = 256;
    bm = (id >> 2) * 64; bn = (id & 3) * 64;
    bp = bias;
  } else {
    int r = id - 64;
    int b = r >> 5, w5 = r & 31;
    A = W + 512; lda = 1024;
    B = kv + (size_t)b * 512 * 512; ldb = 512;
    C = kpE + (size_t)b * 256 * 512; ldc = 512;
    bm = (w5 & 3) * 64; bn = (w5 >> 2) * 64;
  }

  const int l = t & 63, w = t >> 6;
  const int wr = w >> 1, wc = w & 1;
  const int r0 = t >> 3, oc = t & 7;
  const int sw0 = (oc * 16) ^ ((r0 & 7) << 4);

  f32x4 acc[2][2] = {};
  float4 a00, a01, a10, a11, b00, b01, b10, b11;

  auto LOAD = [&](int k0) {
    const float* pa0 = A + (size_t)(bm + r0) * lda + k0 + oc * 8;
    const float* pa1 = pa0 + (size_t)32 * lda;
    a00 = *(const float4*)pa0; a01 = *(const float4*)(pa0 + 4);
    a10 = *(const float4*)pa1; a11 = *(const float4*)(pa1 + 4);
    const float* pb0 = B + (size_t)(bn + r0) * ldb + k0 + oc * 8;
    const float* pb1 = pb0 + (size_t)32 * ldb;
    b00 = *(const float4*)pb0; b01 = *(const float4*)(pb0 + 4);
    b10 = *(const float4*)pb1; b11 = *(const float4*)(pb1 + 4);
  };
  auto WRITE = [&]() {
    *(f16x8*)((char*)sA + r0 * 128 + sw0)        = cvt8(a00, a01);
    *(f16x8*)((char*)sA + (r0 + 32) * 128 + sw0) = cvt8(a10, a11);
    *(f16x8*)((char*)sB + r0 * 128 + sw0)        = cvt8(b00, b01);
    *(f16x8*)((char*)sB + (r0 + 32) * 128 + sw0) = cvt8(b10, b11);
  };

  LOAD(0);
  for (int k0 = 0; k0 < 512; k0 += 64) {
    __syncthreads();
    WRITE();
    if (k0 + 64 < 512) LOAD(k0 + 64);
    __syncthreads();
    mfma_tile(sA, sB, l, wr, wc, acc);
  }

#pragma unroll
  for (int fm = 0; fm < 2; fm++)
#pragma unroll
    for (int fn = 0; fn < 2; fn++) {
      int cn = bn + wc * 32 + fn * 16 + (l & 15);
      float bv = bp ? bp[cn] : 0.0f;
#pragma unroll
      for (int j = 0; j < 4; j++) {
        int rm = bm + wr * 32 + fm * 16 + (l >> 4) * 4 + j;
        C[(size_t)rm * ldc + cn] = __expf((acc[fm][fn][j] + bv) * 2.0f);
      }
    }
}

// ---------------------------------------------------------------------------
// phase 2: fused score + softmax. Unit = 2 q rows x full 512 k (4 waves).
// ---------------------------------------------------------------------------
__device__ void score_phase(
    int id, int t,
    const float* __restrict__ qpE, const float* __restrict__ kpE,
    const float* __restrict__ v,
    const int* __restrict__ qlen_p, const int* __restrict__ klen_p,
    u16* __restrict__ P, float* sm)
{
  const int b = id >> 6, q0 = (id & 63) * 2;
  const int qlen = qlen_p[b], klen = klen_p[b];
  const int w = t >> 6, l = t & 63;
  const int k1 = w * 64 + l, k2 = k1 + 256;
  u16* Pb = P + (size_t)(b * 128 + q0) * 512;

  if (q0 >= qlen) {                   // both rows masked -> uniform 1/512
    const u16 uh = f2fh(1.0f / 512.0f);
    Pb[k1] = uh; Pb[k2] = uh;
    Pb[512 + k1] = uh; Pb[512 + k2] = uh;
    return;
  }

  float* sEq  = sm;                   // [512]
  float* sV2  = sm + 512;             // [256]
  float* sRed = sm + 768;             // [16]

  sV2[t] = 2.0f * v[t];
  sEq[t]       = qpE[(size_t)(b * 128 + q0) * 256 + t];
  sEq[256 + t] = qpE[(size_t)(b * 128 + q0 + 1) * 256 + t];
  __syncthreads();

  const float* kc = kpE + (size_t)b * 256 * 512;
  float s1a = 0.f, s2a = 0.f, s1b = 0.f, s2b = 0.f;

  if (w * 64 < klen) {
    if (256 + w * 64 < klen) {
#pragma unroll 8
      for (int a = 0; a < 256; a++) {
        float ek1 = kc[(size_t)a * 512 + k1];
        float ek2 = kc[(size_t)a * 512 + k2];
        float vv = sV2[a];
        float eqA = sEq[a], eqB = sEq[256 + a];
        s1a = fmaf(-vv, __builtin_amdgcn_rcpf(fmaf(eqA, ek1, 1.0f)), s1a);
        s2a = fmaf(-vv, __builtin_amdgcn_rcpf(fmaf(eqA, ek2, 1.0f)), s2a);
        s1b = fmaf(-vv, __builtin_amdgcn_rcpf(fmaf(eqB, ek1, 1.0f)), s1b);
        s2b = fmaf(-vv, __builtin_amdgcn_rcpf(fmaf(eqB, ek2, 1.0f)), s2b);
      }
    } else {
#pragma unroll 8
      for (int a = 0; a < 256; a++) {
        float ek1 = kc[(size_t)a * 512 + k1];
        float vv = sV2[a];
        float eqA = sEq[a], eqB = sEq[256 + a];
        s1a = fmaf(-vv, __builtin_amdgcn_rcpf(fmaf(eqA, ek1, 1.0f)), s1a);
        s1b = fmaf(-vv, __builtin_amdgcn_rcpf(fmaf(eqB, ek1, 1.0f)), s1b);
      }
    }
  }

  if (k1 >= klen) { s1a = NEGV; s1b = NEGV; }
  if (k2 >= klen) { s2a = NEGV; s2b = NEGV; }

  float mA = fmaxf(s1a, s2a), mB = fmaxf(s1b, s2b);
#pragma unroll
  for (int off = 32; off > 0; off >>= 1) {
    mA = fmaxf(mA, __shfl_xor(mA, off));
    mB = fmaxf(mB, __shfl_xor(mB, off));
  }
  if (l == 0) { sRed[w * 4 + 0] = mA; sRed[w * 4 + 1] = mB; }
  __syncthreads();
  const float MA = fmaxf(fmaxf(sRed[0], sRed[4]), fmaxf(sRed[8],  sRed[12]));
  const float MB = fmaxf(fmaxf(sRed[1], sRed[5]), fmaxf(sRed[9],  sRed[13]));

  float e1a = __expf(s1a - MA), e2a = __expf(s2a - MA);   // masked -> 0
  float e1b = __expf(s1b - MB), e2b = __expf(s2b - MB);
  float suA = e1a + e2a, suB = e1b + e2b;
#pragma unroll
  for (int off = 32; off > 0; off >>= 1) {
    suA += __shfl_xor(suA, off);
    suB += __shfl_xor(suB, off);
  }
  if (l == 0) { sRed[w * 4 + 2] = suA; sRed[w * 4 + 3] = suB; }
  __syncthreads();
  const float SA = (sRed[2] + sRed[6]) + (sRed[10] + sRed[14]);
  const float SB = (sRed[3] + sRed[7]) + (sRed[11] + sRed[15]);
  const float rA = __fdividef(1.0f, SA);
  const float rB = __fdividef(1.0f, SB);

  Pb[k1] = f2fh(e1a * rA);
  Pb[k2] = f2fh(e2a * rA);
  if (q0 + 1 < qlen) {
    Pb[512 + k1] = f2fh(e1b * rB);
    Pb[512 + k2] = f2fh(e2b * rB);
  } else {
    const u16 uh = f2fh(1.0f / 512.0f);
    Pb[512 + k1] = uh;
    Pb[512 + k2] = uh;
  }
}

// ---------------------------------------------------------------------------
// phase 3: pv. out[b] = P[b](fp16) @ kv[b](f32) -- kv tile transposed to
// [d][k] fp16 in LDS during staging; P staged via global_load_lds.
// ---------------------------------------------------------------------------
__device__ void pv_phase(
    int id, int t,
    const u16* __restrict__ P, const float* __restrict__ kv,
    float* __restrict__ out, u16* sA, u16* sB)
{
  const int b = id >> 4, r = id & 15;
  const int bm = (r >> 3) * 64, bn = (r & 7) * 64;

  const u16* Ab = P + (size_t)b * 128 * 512;
  const float* Bb = kv + (size_t)b * 512 * 512;

  const int l = t & 63, w = t >> 6;
  const int wr = w >> 1, wc = w & 1;
  const int srow = l >> 3, scol = ((l & 7) ^ srow) << 3;

  const int dq = t & 15, kq = t >> 4;

  float4 v0, v1, v2, v3;
  auto LOADB = [&](int k0) {
    const float* p = Bb + (size_t)(k0 + kq * 4) * 512 + bn + dq * 4;
    v0 = *(const float4*)p;
    v1 = *(const float4*)(p + 512);
    v2 = *(const float4*)(p + 1024);
    v3 = *(const float4*)(p + 1536);
  };
  auto WRITEB = [&]() {
#define WRB(jj, ee)                                                       \
    { int d = dq * 4 + jj;                                                \
      f16x4 c; c[0] = (_Float16)v0.ee; c[1] = (_Float16)v1.ee;            \
      c[2] = (_Float16)v2.ee; c[3] = (_Float16)v3.ee;                     \
      *(f16x4*)((char*)sB + d * 128 +                                     \
                ((((kq >> 1) * 16) ^ ((d & 7) << 4)) + (kq & 1) * 8)) = c; }
    WRB(0, x) WRB(1, y) WRB(2, z) WRB(3, w)
#undef WRB
  };

  f32x4 acc[2][2] = {};
  LOADB(0);
  for (int k0 = 0; k0 < 512; k0 += 64) {
    __syncthreads();
    WRITEB();
#pragma unroll
    for (int i = 0; i < 2; i++) {
      int s = w * 2 + i;
      gload16(Ab + (size_t)(bm + s * 8 + srow) * 512 + k0 + scol, sA + s * 512);
    }
    if (k0 + 64 < 512) LOADB(k0 + 64);
    __syncthreads();
    mfma_tile(sA, sB, l, wr, wc, acc);
  }

  float* Cb = out + (size_t)b * 128 * 512;
#pragma unroll
  for (int fm = 0; fm < 2; fm++)
#pragma unroll
    for (int fn = 0; fn < 2; fn++) {
      int cn = bn + wc * 32 + fn * 16 + (l & 15);
#pragma unroll
      for (int j = 0; j < 4; j++) {
        int rm = bm + wr * 32 + fm * 16 + (l >> 4) * 4 + j;
        Cb[(size_t)rm * 512 + cn] = acc[fm][fn][j];
      }
    }
}

// ---------------------------------------------------------------------------
// mega: proj -> bar -> score+softmax -> bar -> pv. 512 blocks x 256 threads,
// all co-resident (2 blocks/CU by capacity).
// ---------------------------------------------------------------------------
__global__ __launch_bounds__(256, 2) void mega(
    const float* __restrict__ query, const float* __restrict__ kv,
    const float* __restrict__ W, const float* __restrict__ bias,
    const float* __restrict__ v,
    const int* __restrict__ qlen_p, const int* __restrict__ klen_p,
    float* __restrict__ out,
    float* __restrict__ qpE, float* __restrict__ kpE,
    u16* __restrict__ P, unsigned* __restrict__ bar)
{
  __shared__ __align__(16) unsigned char smem[16384];
  u16* sA = (u16*)smem;
  u16* sB = (u16*)(smem + 8192);
  const int id = blockIdx.x, t = threadIdx.x;

  if (id < 320)
    proj_phase(id, t, query, kv, W, bias, qpE, kpE, sA, sB);

  gridbar(bar, 0, id);

  score_phase(id, t, qpE, kpE, v, qlen_p, klen_p, P, (float*)smem);

  gridbar(bar, 1, id);

  if (id < 128)
    pv_phase(id, t, P, kv, out, sA, sB);
}

// ---------------------------------------------------------------------------
extern "C" void kernel_launch(void* const* d_in, const int* in_sizes, int n_in,
                              void* d_out, int out_size, void* d_ws, size_t ws_size,
                              hipStream_t stream)
{
  const float* query = (const float*)d_in[0];  // [8][128][512]
  const float* kv    = (const float*)d_in[1];  // [8][512][512]
  const float* W     = (const float*)d_in[2];  // [256][1024]
  const float* bbias = (const float*)d_in[3];  // [256]
  const float* v     = (const float*)d_in[4];  // [256]
  const int*   qlen  = (const int*)d_in[5];    // [8]
  const int*   klen  = (const int*)d_in[6];    // [8]
  float* out = (float*)d_out;                  // [8][128][512]

  float*    qpE = (float*)d_ws;                // 1MB
  float*    kpE = qpE + 1024 * 256;            // 4MB
  u16*      P   = (u16*)(kpE + 8 * 256 * 512); // 1MB
  unsigned* bar = (unsigned*)(P + 1024 * 512); // barrier state (~4.2KB used)

  hipMemsetAsync(bar, 0, 8192, stream);

  mega<<<dim3(512), 256, 0, stream>>>(
      query, kv, W, bbias, v, qlen, klen, out, qpE, kpE, P, bar);
}

// Round 11
// 54.429 us; speedup vs baseline: 4.1931x; 4.1931x over previous
//
#include <hip/hip_runtime.h>

#define NEGV (-10000000000.0f)

typedef unsigned short u16;
typedef _Float16 __attribute__((ext_vector_type(8))) f16x8;
typedef __attribute__((ext_vector_type(4))) float f32x4;

__device__ __forceinline__ f16x8 cvt8(float4 x, float4 y) {
  f16x8 o;
  o[0] = (_Float16)x.x; o[1] = (_Float16)x.y;
  o[2] = (_Float16)x.z; o[3] = (_Float16)x.w;
  o[4] = (_Float16)y.x; o[5] = (_Float16)y.y;
  o[6] = (_Float16)y.z; o[7] = (_Float16)y.w;
  return o;
}

// ---------------------------------------------------------------------------
// shared MFMA inner step: 64x64 tile in sA/sB ([row][64 fp16] = 128B rows,
// oct-granular XOR swizzle byte ^= (row&7)<<4), 4 waves (2x2), 2x2 fragments.
// ---------------------------------------------------------------------------
__device__ __forceinline__ void mfma_tile(const u16* sA, const u16* sB,
                                          int l, int wr, int wc,
                                          f32x4 (*acc)[2]) {
#pragma unroll
  for (int ks = 0; ks < 2; ks++) {
    f16x8 af[2], bfr[2];
#pragma unroll
    for (int f = 0; f < 2; f++) {
      int cb = (ks * 32 + ((l >> 4) << 3)) << 1;
      int row = wr * 32 + f * 16 + (l & 15);
      af[f] = *(const f16x8*)((const char*)sA + row * 128 + (cb ^ ((row & 7) << 4)));
      int col = wc * 32 + f * 16 + (l & 15);
      bfr[f] = *(const f16x8*)((const char*)sB + col * 128 + (cb ^ ((col & 7) << 4)));
    }
#pragma unroll
    for (int fm = 0; fm < 2; fm++)
#pragma unroll
      for (int fn = 0; fn < 2; fn++)
        acc[fm][fn] = __builtin_amdgcn_mfma_f32_16x16x32_f16(
            af[fm], bfr[fn], acc[fm][fn], 0, 0, 0);
  }
}

// ---------------------------------------------------------------------------
// dispatch 1: proj (blocks 0..319) + kv column sums (blocks 320..383).
// proj: f32 inputs, in-register fp16 convert into swizzled LDS, MFMA,
// epilogue exp(2*(acc+bias)).
//   blocks 0..63:  qpE = exp(2(query·Wq^T + b))  [1024][256]
//   blocks 64..319: kpE = exp(2(Wk·kv[b]^T))     [b][256 a][512 k]
// colsum: kvsum[b][d] = sum_k kv[b][k][d]  (f32 atomics, zeroed by memset)
// ---------------------------------------------------------------------------
__global__ __launch_bounds__(256) void proj_colsum(
    const float* __restrict__ query, const float* __restrict__ kv,
    const float* __restrict__ W, const float* __restrict__ bias,
    float* __restrict__ qpE, float* __restrict__ kpE,
    float* __restrict__ kvsum)
{
  const int id = blockIdx.x, t = threadIdx.x;

  if (id >= 320) {                       // ---- colsum ----
    const int cb = id - 320;             // 0..63
    const int b = cb >> 3, kt = cb & 7;  // 64 k-rows per block
    const float* p = kv + ((size_t)b * 512 + kt * 64) * 512 + 2 * t;
    float s0 = 0.f, s1 = 0.f;
#pragma unroll 8
    for (int kk = 0; kk < 64; kk++) {
      float2 x = *(const float2*)(p + (size_t)kk * 512);
      s0 += x.x; s1 += x.y;
    }
    atomicAdd(&kvsum[b * 512 + 2 * t], s0);
    atomicAdd(&kvsum[b * 512 + 2 * t + 1], s1);
    return;
  }

  __shared__ __align__(16) u16 sA[8 * 512];   // 64 rows x 64 fp16
  __shared__ __align__(16) u16 sB[8 * 512];

  const float *A, *B; float* C;
  int lda, ldb, ldc, bm, bn;
  const float* bp = nullptr;
  if (id < 64) {
    A = query; lda = 512; B = W; ldb = 1024;
    C = qpE; ldc = 256;
    bm = (id >> 2) * 64; bn = (id & 3) * 64;
    bp = bias;
  } else {
    int r = id - 64;
    int b = r >> 5, w5 = r & 31;
    A = W + 512; lda = 1024;
    B = kv + (size_t)b * 512 * 512; ldb = 512;
    C = kpE + (size_t)b * 256 * 512; ldc = 512;
    bm = (w5 & 3) * 64; bn = (w5 >> 2) * 64;
  }

  const int l = t & 63, w = t >> 6;
  const int wr = w >> 1, wc = w & 1;
  const int r0 = t >> 3, oc = t & 7;
  const int sw0 = (oc * 16) ^ ((r0 & 7) << 4);

  f32x4 acc[2][2] = {};
  float4 a00, a01, a10, a11, b00, b01, b10, b11;

  auto LOAD = [&](int k0) {
    const float* pa0 = A + (size_t)(bm + r0) * lda + k0 + oc * 8;
    const float* pa1 = pa0 + (size_t)32 * lda;
    a00 = *(const float4*)pa0; a01 = *(const float4*)(pa0 + 4);
    a10 = *(const float4*)pa1; a11 = *(const float4*)(pa1 + 4);
    const float* pb0 = B + (size_t)(bn + r0) * ldb + k0 + oc * 8;
    const float* pb1 = pb0 + (size_t)32 * ldb;
    b00 = *(const float4*)pb0; b01 = *(const float4*)(pb0 + 4);
    b10 = *(const float4*)pb1; b11 = *(const float4*)(pb1 + 4);
  };
  auto WRITE = [&]() {
    *(f16x8*)((char*)sA + r0 * 128 + sw0)        = cvt8(a00, a01);
    *(f16x8*)((char*)sA + (r0 + 32) * 128 + sw0) = cvt8(a10, a11);
    *(f16x8*)((char*)sB + r0 * 128 + sw0)        = cvt8(b00, b01);
    *(f16x8*)((char*)sB + (r0 + 32) * 128 + sw0) = cvt8(b10, b11);
  };

  LOAD(0);
  for (int k0 = 0; k0 < 512; k0 += 64) {
    __syncthreads();
    WRITE();
    if (k0 + 64 < 512) LOAD(k0 + 64);
    __syncthreads();
    mfma_tile(sA, sB, l, wr, wc, acc);
  }

#pragma unroll
  for (int fm = 0; fm < 2; fm++)
#pragma unroll
    for (int fn = 0; fn < 2; fn++) {
      int cn = bn + wc * 32 + fn * 16 + (l & 15);
      float bv = bp ? bp[cn] : 0.0f;
#pragma unroll
      for (int j = 0; j < 4; j++) {
        int rm = bm + wr * 32 + fm * 16 + (l >> 4) * 4 + j;
        C[(size_t)rm * ldc + cn] = __expf((acc[fm][fn][j] + bv) * 2.0f);
      }
    }
}

// ---------------------------------------------------------------------------
// dispatch 2: fused score + softmax + PV. Block = 4 q rows (8 waves, 512 thr),
// grid (32, 8). score'[q,k] = -sum_a 2 v_a / (1 + eq[q][a]*ek[a][k]) which is
// the true score minus a per-q constant -> identical softmax.
// Lane owns k = t for scoring; P kept in LDS f32 sW[k][4].
// PV: wave w sums k-chunk [w*64, ...), lane owns d in {l, l+64, ..., l+448};
// partials combined via sAcc (2-pass, conflict-free). Masked rows <- kvsum/512.
// ---------------------------------------------------------------------------
__global__ __launch_bounds__(512) void score_pv(
    const float* __restrict__ qpE,    // [B*128][256] = exp(2(qp+b))
    const float* __restrict__ kpE,    // [B][256][512] = exp(2kp)
    const float* __restrict__ v,      // [256]
    const int* __restrict__ qlen_p, const int* __restrict__ klen_p,
    const float* __restrict__ kv,     // [B][512][512]
    const float* __restrict__ kvsum,  // [B][512]
    float* __restrict__ out)          // [B][128][512]
{
  const int b = blockIdx.y, q0 = blockIdx.x * 4, t = threadIdx.x;
  const int qlen = qlen_p[b], klen = klen_p[b];
  float* outb = out + (size_t)(b * 128 + q0) * 512;

  if (q0 >= qlen) {                   // all 4 rows masked -> mean(kv[b])
    float m = kvsum[b * 512 + t] * (1.0f / 512.0f);
#pragma unroll
    for (int r = 0; r < 4; r++) outb[(size_t)r * 512 + t] = m;
    return;
  }

  __shared__ float sW[512][4];        // 8KB  P (f32)
  __shared__ float sEq[256][4];       // 4KB  eq rows, transposed for b128
  __shared__ float sV2[256];          // 1KB
  __shared__ float sRed[8][8];        // [wave][r:max(0..3), r:sum(4..7)]
  __shared__ float sAcc[4][4 * 512];  // 32KB PV partials

  {
    int a = t & 255, rr = t >> 8;     // rr = 0,1
    sEq[a][rr]     = qpE[(size_t)(b * 128 + q0 + rr) * 256 + a];
    sEq[a][rr + 2] = qpE[(size_t)(b * 128 + q0 + rr + 2) * 256 + a];
    if (t < 256) sV2[t] = 2.0f * v[t];
  }
  __syncthreads();

  const int w = t >> 6, l = t & 63;
  const int k = t;                    // 0..511

  // ---- score ----
  float s[4] = {0.f, 0.f, 0.f, 0.f};
  if (w * 64 < klen) {
    const float* kc = kpE + (size_t)b * 256 * 512 + k;
#pragma unroll 8
    for (int a = 0; a < 256; a++) {
      float ek = kc[(size_t)a * 512];
      f32x4 eq = *(const f32x4*)&sEq[a][0];
      float vv = sV2[a];
#pragma unroll
      for (int r = 0; r < 4; r++)
        s[r] = fmaf(-vv, __builtin_amdgcn_rcpf(fmaf(eq[r], ek, 1.0f)), s[r]);
    }
  }
  if (k >= klen) {
#pragma unroll
    for (int r = 0; r < 4; r++) s[r] = NEGV;
  }

  // ---- softmax (per-row over 512 lanes: wave shuffle + 8-wave LDS) ----
#pragma unroll
  for (int r = 0; r < 4; r++) {
    float x = s[r];
#pragma unroll
    for (int off = 32; off > 0; off >>= 1) x = fmaxf(x, __shfl_xor(x, off));
    if (l == 0) sRed[w][r] = x;
  }
  __syncthreads();
  float e[4];
#pragma unroll
  for (int r = 0; r < 4; r++) {
    float mm = sRed[0][r];
#pragma unroll
    for (int i = 1; i < 8; i++) mm = fmaxf(mm, sRed[i][r]);
    e[r] = __expf(s[r] - mm);         // k>=klen -> exact 0
  }
  __syncthreads();                    // sRed reuse for sums
#pragma unroll
  for (int r = 0; r < 4; r++) {
    float x = e[r];
#pragma unroll
    for (int off = 32; off > 0; off >>= 1) x += __shfl_xor(x, off);
    if (l == 0) sRed[w][4 + r] = x;
  }
  __syncthreads();
  f32x4 p;
#pragma unroll
  for (int r = 0; r < 4; r++) {
    float S = 0.f;
#pragma unroll
    for (int i = 0; i < 8; i++) S += sRed[i][4 + r];
    p[r] = e[r] * __fdividef(1.0f, S);
  }
  *(f32x4*)&sW[k][0] = p;
  __syncthreads();

  // ---- PV: wave w covers k in [w*64, min(w*64+64, klen)) ----
  f32x4 accA[4] = {}, accB[4] = {};   // acc[r][j]: j 0..3 in A, 4..7 in B
  const int kb = w * 64;
  const int ke = (kb + 64 < klen) ? kb + 64 : klen;
  const float* kvb = kv + (size_t)b * 512 * 512 + l;
#pragma unroll 4
  for (int kk = kb; kk < ke; kk++) {
    f32x4 p4 = *(const f32x4*)&sW[kk][0];       // uniform b128
    const float* row = kvb + (size_t)kk * 512;
    float x[8];
#pragma unroll
    for (int j = 0; j < 8; j++) x[j] = row[j * 64];
#pragma unroll
    for (int r = 0; r < 4; r++)
#pragma unroll
      for (int j = 0; j < 4; j++) {
        accA[r][j] = fmaf(p4[r], x[j],     accA[r][j]);
        accB[r][j] = fmaf(p4[r], x[4 + j], accB[r][j]);
      }
  }

  if (w < 4) {                        // pass 1: write
#pragma unroll
    for (int r = 0; r < 4; r++)
#pragma unroll
      for (int j = 0; j < 8; j++)
        sAcc[w][r * 512 + l + j * 64] = (j < 4) ? accA[r][j] : accB[r][j - 4];
  }
  __syncthreads();
  if (w >= 4) {                       // pass 2: accumulate
#pragma unroll
    for (int r = 0; r < 4; r++)
#pragma unroll
      for (int j = 0; j < 8; j++)
        sAcc[w - 4][r * 512 + l + j * 64] += (j < 4) ? accA[r][j] : accB[r][j - 4];
  }
  __syncthreads();

  // ---- combine 4 partials + masked-row fixup + store ----
#pragma unroll
  for (int r = 0; r < 4; r++) {
    float val = (sAcc[0][r * 512 + t] + sAcc[1][r * 512 + t]) +
                (sAcc[2][r * 512 + t] + sAcc[3][r * 512 + t]);
    if (q0 + r >= qlen) val = kvsum[b * 512 + t] * (1.0f / 512.0f);
    outb[(size_t)r * 512 + t] = val;
  }
}

// ---------------------------------------------------------------------------
extern "C" void kernel_launch(void* const* d_in, const int* in_sizes, int n_in,
                              void* d_out, int out_size, void* d_ws, size_t ws_size,
                              hipStream_t stream)
{
  const float* query = (const float*)d_in[0];  // [8][128][512]
  const float* kv    = (const float*)d_in[1];  // [8][512][512]
  const float* W     = (const float*)d_in[2];  // [256][1024]
  const float* bbias = (const float*)d_in[3];  // [256]
  const float* v     = (const float*)d_in[4];  // [256]
  const int*   qlen  = (const int*)d_in[5];    // [8]
  const int*   klen  = (const int*)d_in[6];    // [8]
  float* out = (float*)d_out;                  // [8][128][512]

  float* qpE   = (float*)d_ws;                 // 1MB
  float* kpE   = qpE + 1024 * 256;             // 4MB
  float* kvsum = kpE + 8 * 256 * 512;          // 16KB

  hipMemsetAsync(kvsum, 0, 8 * 512 * sizeof(float), stream);

  proj_colsum<<<dim3(384), 256, 0, stream>>>(
      query, kv, W, bbias, qpE, kpE, kvsum);

  score_pv<<<dim3(32, 8), 512, 0, stream>>>(
      qpE, kpE, v, qlen, klen, kv, kvsum, out);
}

// Round 12
// 44.635 us; speedup vs baseline: 5.1132x; 1.2194x over previous
//
#include <hip/hip_runtime.h>

#define NEGV (-10000000000.0f)

typedef unsigned short u16;
typedef _Float16 __attribute__((ext_vector_type(8))) f16x8;
typedef _Float16 __attribute__((ext_vector_type(4))) f16x4;
typedef __attribute__((ext_vector_type(4))) float f32x4;

__device__ __forceinline__ u16 f2fh(float f) {
  _Float16 h = (_Float16)f;
  return __builtin_bit_cast(u16, h);
}

__device__ __forceinline__ void gload16(const u16* g, u16* l) {
  __builtin_amdgcn_global_load_lds(
      (const __attribute__((address_space(1))) void*)g,
      (__attribute__((address_space(3))) void*)l, 16, 0, 0);
}

__device__ __forceinline__ f16x8 cvt8(float4 x, float4 y) {
  f16x8 o;
  o[0] = (_Float16)x.x; o[1] = (_Float16)x.y;
  o[2] = (_Float16)x.z; o[3] = (_Float16)x.w;
  o[4] = (_Float16)y.x; o[5] = (_Float16)y.y;
  o[6] = (_Float16)y.z; o[7] = (_Float16)y.w;
  return o;
}

// ---------------------------------------------------------------------------
// shared MFMA inner step: 64x64 tile in sA/sB ([row][64 fp16] = 128B rows,
// oct-granular XOR swizzle byte ^= (row&7)<<4), 4 waves (2x2), 2x2 fragments.
// ---------------------------------------------------------------------------
__device__ __forceinline__ void mfma_tile(const u16* sA, const u16* sB,
                                          int l, int wr, int wc,
                                          f32x4 (*acc)[2]) {
#pragma unroll
  for (int ks = 0; ks < 2; ks++) {
    f16x8 af[2], bfr[2];
#pragma unroll
    for (int f = 0; f < 2; f++) {
      int cb = (ks * 32 + ((l >> 4) << 3)) << 1;
      int row = wr * 32 + f * 16 + (l & 15);
      af[f] = *(const f16x8*)((const char*)sA + row * 128 + (cb ^ ((row & 7) << 4)));
      int col = wc * 32 + f * 16 + (l & 15);
      bfr[f] = *(const f16x8*)((const char*)sB + col * 128 + (cb ^ ((col & 7) << 4)));
    }
#pragma unroll
    for (int fm = 0; fm < 2; fm++)
#pragma unroll
      for (int fn = 0; fn < 2; fn++)
        acc[fm][fn] = __builtin_amdgcn_mfma_f32_16x16x32_f16(
            af[fm], bfr[fn], acc[fm][fn], 0, 0, 0);
  }
}

// ---------------------------------------------------------------------------
// dispatch 1: proj. f32 inputs, in-register fp16 convert into swizzled LDS,
// MFMA, epilogue exp(2*(acc+bias)).
//   blocks 0..63:  qpE = exp(2(query·Wq^T + b))  [1024][256]
//   blocks 64..319: kpE = exp(2(Wk·kv[b]^T))     [b][256 a][512 k]
// ---------------------------------------------------------------------------
__global__ __launch_bounds__(256) void proj_mfma(
    const float* __restrict__ query, const float* __restrict__ kv,
    const float* __restrict__ W, const float* __restrict__ bias,
    float* __restrict__ qpE, float* __restrict__ kpE)
{
  __shared__ __align__(16) u16 sA[8 * 512];   // 64 rows x 64 fp16
  __shared__ __align__(16) u16 sB[8 * 512];
  const int id = blockIdx.x, t = threadIdx.x;

  const float *A, *B; float* C;
  int lda, ldb, ldc, bm, bn;
  const float* bp = nullptr;
  if (id < 64) {
    A = query; lda = 512; B = W; ldb = 1024;
    C = qpE; ldc = 256;
    bm = (id >> 2) * 64; bn = (id & 3) * 64;
    bp = bias;
  } else {
    int r = id - 64;
    int b = r >> 5, w5 = r & 31;
    A = W + 512; lda = 1024;
    B = kv + (size_t)b * 512 * 512; ldb = 512;
    C = kpE + (size_t)b * 256 * 512; ldc = 512;
    bm = (w5 & 3) * 64; bn = (w5 >> 2) * 64;
  }

  const int l = t & 63, w = t >> 6;
  const int wr = w >> 1, wc = w & 1;
  const int r0 = t >> 3, oc = t & 7;
  const int sw0 = (oc * 16) ^ ((r0 & 7) << 4);

  f32x4 acc[2][2] = {};
  float4 a00, a01, a10, a11, b00, b01, b10, b11;

  auto LOAD = [&](int k0) {
    const float* pa0 = A + (size_t)(bm + r0) * lda + k0 + oc * 8;
    const float* pa1 = pa0 + (size_t)32 * lda;
    a00 = *(const float4*)pa0; a01 = *(const float4*)(pa0 + 4);
    a10 = *(const float4*)pa1; a11 = *(const float4*)(pa1 + 4);
    const float* pb0 = B + (size_t)(bn + r0) * ldb + k0 + oc * 8;
    const float* pb1 = pb0 + (size_t)32 * ldb;
    b00 = *(const float4*)pb0; b01 = *(const float4*)(pb0 + 4);
    b10 = *(const float4*)pb1; b11 = *(const float4*)(pb1 + 4);
  };
  auto WRITE = [&]() {
    *(f16x8*)((char*)sA + r0 * 128 + sw0)        = cvt8(a00, a01);
    *(f16x8*)((char*)sA + (r0 + 32) * 128 + sw0) = cvt8(a10, a11);
    *(f16x8*)((char*)sB + r0 * 128 + sw0)        = cvt8(b00, b01);
    *(f16x8*)((char*)sB + (r0 + 32) * 128 + sw0) = cvt8(b10, b11);
  };

  LOAD(0);
  for (int k0 = 0; k0 < 512; k0 += 64) {
    __syncthreads();
    WRITE();
    if (k0 + 64 < 512) LOAD(k0 + 64);
    __syncthreads();
    mfma_tile(sA, sB, l, wr, wc, acc);
  }

#pragma unroll
  for (int fm = 0; fm < 2; fm++)
#pragma unroll
    for (int fn = 0; fn < 2; fn++) {
      int cn = bn + wc * 32 + fn * 16 + (l & 15);
      float bv = bp ? bp[cn] : 0.0f;
#pragma unroll
      for (int j = 0; j < 4; j++) {
        int rm = bm + wr * 32 + fm * 16 + (l >> 4) * 4 + j;
        C[(size_t)rm * ldc + cn] = __expf((acc[fm][fn][j] + bv) * 2.0f);
      }
    }
}

// ---------------------------------------------------------------------------
// dispatch 2: fused score + softmax. Block = 4 q rows x full 512 k
// (512 threads, 8 waves; lane owns k = t). Grid (32, 8).
// score'[q,k] = -sum_a 2 v_a / (1 + eq[q][a]*ek[a][k]) (softmax-equivalent).
// P fp16: masked q -> uniform 1/512 (PV GEMM then yields mean(kv) exactly);
// k>=klen -> exact 0 via exp(NEGV - M).
// ---------------------------------------------------------------------------
__global__ __launch_bounds__(512) void score_softmax(
    const float* __restrict__ qpE,    // [B*128][256] = exp(2(qp+b))
    const float* __restrict__ kpE,    // [B][256][512] = exp(2kp)
    const float* __restrict__ v,      // [256]
    const int* __restrict__ qlen_p, const int* __restrict__ klen_p,
    u16* __restrict__ P)              // [B][128][512] fp16
{
  const int b = blockIdx.y, q0 = blockIdx.x * 4, t = threadIdx.x;
  const int qlen = qlen_p[b], klen = klen_p[b];
  const int w = t >> 6, l = t & 63;
  const int k = t;                    // 0..511
  u16* Pb = P + (size_t)(b * 128 + q0) * 512;

  if (q0 >= qlen) {                   // all 4 rows masked -> uniform 1/512
    const u16 uh = f2fh(1.0f / 512.0f);
#pragma unroll
    for (int r = 0; r < 4; r++) Pb[(size_t)r * 512 + k] = uh;
    return;
  }

  __shared__ float sEq[256][4];       // [a][row], uniform-broadcast reads
  __shared__ float sV2[256];
  __shared__ float sRed[8][8];        // [wave][r:max 0..3, r:sum 4..7]

  {
    int a = t & 255, rr = t >> 8;     // rr = 0,1
    sEq[a][rr]     = qpE[(size_t)(b * 128 + q0 + rr) * 256 + a];
    sEq[a][rr + 2] = qpE[(size_t)(b * 128 + q0 + rr + 2) * 256 + a];
    if (t < 256) sV2[t] = 2.0f * v[t];
  }
  __syncthreads();

  // ---- score ----
  float s[4] = {0.f, 0.f, 0.f, 0.f};
  if (w * 64 < klen) {                // wave has at least one active k
    const float* kc = kpE + (size_t)b * 256 * 512 + k;
#pragma unroll 8
    for (int a = 0; a < 256; a++) {
      float ek = kc[(size_t)a * 512];
      f32x4 eq = *(const f32x4*)&sEq[a][0];
      float vv = sV2[a];
#pragma unroll
      for (int r = 0; r < 4; r++)
        s[r] = fmaf(-vv, __builtin_amdgcn_rcpf(fmaf(eq[r], ek, 1.0f)), s[r]);
    }
  }
  if (k >= klen) {
#pragma unroll
    for (int r = 0; r < 4; r++) s[r] = NEGV;
  }

  // ---- softmax over 512 lanes (wave shuffle + 8-wave LDS combine) ----
#pragma unroll
  for (int r = 0; r < 4; r++) {
    float x = s[r];
#pragma unroll
    for (int off = 32; off > 0; off >>= 1) x = fmaxf(x, __shfl_xor(x, off));
    if (l == 0) sRed[w][r] = x;
  }
  __syncthreads();
  float e[4];
#pragma unroll
  for (int r = 0; r < 4; r++) {
    float mm = fmaxf(fmaxf(sRed[0][r], sRed[1][r]),
                     fmaxf(sRed[2][r], sRed[3][r]));
    mm = fmaxf(mm, fmaxf(fmaxf(sRed[4][r], sRed[5][r]),
                         fmaxf(sRed[6][r], sRed[7][r])));
    e[r] = __expf(s[r] - mm);         // k>=klen -> exact 0
  }
  __syncthreads();                    // sRed reuse
#pragma unroll
  for (int r = 0; r < 4; r++) {
    float x = e[r];
#pragma unroll
    for (int off = 32; off > 0; off >>= 1) x += __shfl_xor(x, off);
    if (l == 0) sRed[w][4 + r] = x;
  }
  __syncthreads();

  const u16 uh = f2fh(1.0f / 512.0f);
#pragma unroll
  for (int r = 0; r < 4; r++) {
    float S = (sRed[0][4 + r] + sRed[1][4 + r]) +
              (sRed[2][4 + r] + sRed[3][4 + r]) +
              (sRed[4][4 + r] + sRed[5][4 + r]) +
              (sRed[6][4 + r] + sRed[7][4 + r]);
    float p = e[r] * __fdividef(1.0f, S);
    Pb[(size_t)r * 512 + k] = (q0 + r < qlen) ? f2fh(p) : uh;
  }
}

// ---------------------------------------------------------------------------
// dispatch 3: pv. out[b] = P[b](fp16) @ kv[b](f32) -- kv tile transposed to
// [d][k] fp16 in LDS during staging; P staged via global_load_lds.
// 128 blocks: b(8) x mt(2) x nt(8).
// ---------------------------------------------------------------------------
__global__ __launch_bounds__(256) void pv_mfma(
    const u16* __restrict__ P, const float* __restrict__ kv,
    float* __restrict__ out)
{
  __shared__ __align__(16) u16 sA[8 * 512];
  __shared__ __align__(16) u16 sB[8 * 512];
  const int id = blockIdx.x, t = threadIdx.x;
  const int b = id >> 4, r = id & 15;
  const int bm = (r >> 3) * 64, bn = (r & 7) * 64;

  const u16* Ab = P + (size_t)b * 128 * 512;
  const float* Bb = kv + (size_t)b * 512 * 512;

  const int l = t & 63, w = t >> 6;
  const int wr = w >> 1, wc = w & 1;
  const int srow = l >> 3, scol = ((l & 7) ^ srow) << 3;

  const int dq = t & 15, kq = t >> 4;

  float4 v0, v1, v2, v3;
  auto LOADB = [&](int k0) {
    const float* p = Bb + (size_t)(k0 + kq * 4) * 512 + bn + dq * 4;
    v0 = *(const float4*)p;
    v1 = *(const float4*)(p + 512);
    v2 = *(const float4*)(p + 1024);
    v3 = *(const float4*)(p + 1536);
  };
  auto WRITEB = [&]() {
#define WRB(jj, ee)                                                       \
    { int d = dq * 4 + jj;                                                \
      f16x4 c; c[0] = (_Float16)v0.ee; c[1] = (_Float16)v1.ee;            \
      c[2] = (_Float16)v2.ee; c[3] = (_Float16)v3.ee;                     \
      *(f16x4*)((char*)sB + d * 128 +                                     \
                ((((kq >> 1) * 16) ^ ((d & 7) << 4)) + (kq & 1) * 8)) = c; }
    WRB(0, x) WRB(1, y) WRB(2, z) WRB(3, w)
#undef WRB
  };

  f32x4 acc[2][2] = {};
  LOADB(0);
  for (int k0 = 0; k0 < 512; k0 += 64) {
    __syncthreads();
    WRITEB();
#pragma unroll
    for (int i = 0; i < 2; i++) {
      int s = w * 2 + i;
      gload16(Ab + (size_t)(bm + s * 8 + srow) * 512 + k0 + scol, sA + s * 512);
    }
    if (k0 + 64 < 512) LOADB(k0 + 64);
    __syncthreads();
    mfma_tile(sA, sB, l, wr, wc, acc);
  }

  float* Cb = out + (size_t)b * 128 * 512;
#pragma unroll
  for (int fm = 0; fm < 2; fm++)
#pragma unroll
    for (int fn = 0; fn < 2; fn++) {
      int cn = bn + wc * 32 + fn * 16 + (l & 15);
#pragma unroll
      for (int j = 0; j < 4; j++) {
        int rm = bm + wr * 32 + fm * 16 + (l >> 4) * 4 + j;
        Cb[(size_t)rm * 512 + cn] = acc[fm][fn][j];
      }
    }
}

// ---------------------------------------------------------------------------
extern "C" void kernel_launch(void* const* d_in, const int* in_sizes, int n_in,
                              void* d_out, int out_size, void* d_ws, size_t ws_size,
                              hipStream_t stream)
{
  const float* query = (const float*)d_in[0];  // [8][128][512]
  const float* kv    = (const float*)d_in[1];  // [8][512][512]
  const float* W     = (const float*)d_in[2];  // [256][1024]
  const float* bbias = (const float*)d_in[3];  // [256]
  const float* v     = (const float*)d_in[4];  // [256]
  const int*   qlen  = (const int*)d_in[5];    // [8]
  const int*   klen  = (const int*)d_in[6];    // [8]
  float* out = (float*)d_out;                  // [8][128][512]

  float* qpE = (float*)d_ws;                   // 1MB
  float* kpE = qpE + 1024 * 256;               // 4MB
  u16*   P   = (u16*)(kpE + 8 * 256 * 512);    // 1MB

  proj_mfma<<<dim3(320), 256, 0, stream>>>(query, kv, W, bbias, qpE, kpE);

  score_softmax<<<dim3(32, 8), 512, 0, stream>>>(
      qpE, kpE, v, qlen, klen, P);

  pv_mfma<<<dim3(128), 256, 0, stream>>>(P, kv, out);
}

// Round 13
// 40.402 us; speedup vs baseline: 5.6490x; 1.1048x over previous
//
#include <hip/hip_runtime.h>

#define NEGV (-10000000000.0f)

typedef unsigned short u16;
typedef _Float16 __attribute__((ext_vector_type(8))) f16x8;
typedef _Float16 __attribute__((ext_vector_type(4))) f16x4;
typedef __attribute__((ext_vector_type(4))) float f32x4;

__device__ __forceinline__ u16 f2fh(float f) {
  _Float16 h = (_Float16)f;
  return __builtin_bit_cast(u16, h);
}

__device__ __forceinline__ void gload16(const u16* g, u16* l) {
  __builtin_amdgcn_global_load_lds(
      (const __attribute__((address_space(1))) void*)g,
      (__attribute__((address_space(3))) void*)l, 16, 0, 0);
}

__device__ __forceinline__ f16x8 cvt8(float4 x, float4 y) {
  f16x8 o;
  o[0] = (_Float16)x.x; o[1] = (_Float16)x.y;
  o[2] = (_Float16)x.z; o[3] = (_Float16)x.w;
  o[4] = (_Float16)y.x; o[5] = (_Float16)y.y;
  o[6] = (_Float16)y.z; o[7] = (_Float16)y.w;
  return o;
}

// ---------------------------------------------------------------------------
// shared MFMA inner step: 64x64 tile in sA/sB ([row][64 fp16] = 128B rows,
// oct-granular XOR swizzle byte ^= (row&7)<<4), 4 waves (2x2), 2x2 fragments.
// ---------------------------------------------------------------------------
__device__ __forceinline__ void mfma_tile(const u16* sA, const u16* sB,
                                          int l, int wr, int wc,
                                          f32x4 (*acc)[2]) {
#pragma unroll
  for (int ks = 0; ks < 2; ks++) {
    f16x8 af[2], bfr[2];
#pragma unroll
    for (int f = 0; f < 2; f++) {
      int cb = (ks * 32 + ((l >> 4) << 3)) << 1;
      int row = wr * 32 + f * 16 + (l & 15);
      af[f] = *(const f16x8*)((const char*)sA + row * 128 + (cb ^ ((row & 7) << 4)));
      int col = wc * 32 + f * 16 + (l & 15);
      bfr[f] = *(const f16x8*)((const char*)sB + col * 128 + (cb ^ ((col & 7) << 4)));
    }
#pragma unroll
    for (int fm = 0; fm < 2; fm++)
#pragma unroll
      for (int fn = 0; fn < 2; fn++)
        acc[fm][fn] = __builtin_amdgcn_mfma_f32_16x16x32_f16(
            af[fm], bfr[fn], acc[fm][fn], 0, 0, 0);
  }
}

// ---------------------------------------------------------------------------
// dispatch 1: proj. XCD-swizzled (320 = 8x40, bijective). Masked tiles skip.
//   logical 0..63:  qpE = exp(2(query·Wq^T + b))  [1024][256]
//   logical 64..319: kpE = exp(2(Wk·kv[b]^T))     [b][256 a][512 k]
// f32 inputs, in-register fp16 convert into swizzled LDS, MFMA epilogue exp.
// ---------------------------------------------------------------------------
__global__ __launch_bounds__(256) void proj_mfma(
    const float* __restrict__ query, const float* __restrict__ kv,
    const float* __restrict__ W, const float* __restrict__ bias,
    const int* __restrict__ qlen_p, const int* __restrict__ klen_p,
    float* __restrict__ qpE, float* __restrict__ kpE)
{
  const int p = blockIdx.x;
  const int id = (p & 7) * 40 + (p >> 3);       // XCD-chunked logical id
  const int t = threadIdx.x;

  const float *A, *B; float* C;
  int lda, ldb, ldc, bm, bn;
  const float* bp = nullptr;
  if (id < 64) {
    bm = (id >> 2) * 64; bn = (id & 3) * 64;
    // skip fully-masked q-tile (64-row tile lies inside one 128-row batch)
    if ((bm & 127) >= qlen_p[bm >> 7]) return;
    A = query; lda = 512; B = W; ldb = 1024;
    C = qpE; ldc = 256;
    bp = bias;
  } else {
    int r = id - 64;
    int b = r >> 5, w5 = r & 31;
    bm = (w5 & 3) * 64; bn = (w5 >> 2) * 64;
    if (bn >= klen_p[b]) return;                // skip fully-masked k-tile
    A = W + 512; lda = 1024;
    B = kv + (size_t)b * 512 * 512; ldb = 512;
    C = kpE + (size_t)b * 256 * 512; ldc = 512;
  }

  __shared__ __align__(16) u16 sA[8 * 512];     // 64 rows x 64 fp16
  __shared__ __align__(16) u16 sB[8 * 512];

  const int l = t & 63, w = t >> 6;
  const int wr = w >> 1, wc = w & 1;
  const int r0 = t >> 3, oc = t & 7;
  const int sw0 = (oc * 16) ^ ((r0 & 7) << 4);

  f32x4 acc[2][2] = {};
  float4 a00, a01, a10, a11, b00, b01, b10, b11;

  auto LOAD = [&](int k0) {
    const float* pa0 = A + (size_t)(bm + r0) * lda + k0 + oc * 8;
    const float* pa1 = pa0 + (size_t)32 * lda;
    a00 = *(const float4*)pa0; a01 = *(const float4*)(pa0 + 4);
    a10 = *(const float4*)pa1; a11 = *(const float4*)(pa1 + 4);
    const float* pb0 = B + (size_t)(bn + r0) * ldb + k0 + oc * 8;
    const float* pb1 = pb0 + (size_t)32 * ldb;
    b00 = *(const float4*)pb0; b01 = *(const float4*)(pb0 + 4);
    b10 = *(const float4*)pb1; b11 = *(const float4*)(pb1 + 4);
  };
  auto WRITE = [&]() {
    *(f16x8*)((char*)sA + r0 * 128 + sw0)        = cvt8(a00, a01);
    *(f16x8*)((char*)sA + (r0 + 32) * 128 + sw0) = cvt8(a10, a11);
    *(f16x8*)((char*)sB + r0 * 128 + sw0)        = cvt8(b00, b01);
    *(f16x8*)((char*)sB + (r0 + 32) * 128 + sw0) = cvt8(b10, b11);
  };

  LOAD(0);
  for (int k0 = 0; k0 < 512; k0 += 64) {
    __syncthreads();
    WRITE();
    if (k0 + 64 < 512) LOAD(k0 + 64);
    __syncthreads();
    mfma_tile(sA, sB, l, wr, wc, acc);
  }

#pragma unroll
  for (int fm = 0; fm < 2; fm++)
#pragma unroll
    for (int fn = 0; fn < 2; fn++) {
      int cn = bn + wc * 32 + fn * 16 + (l & 15);
      float bv = bp ? bp[cn] : 0.0f;
#pragma unroll
      for (int j = 0; j < 4; j++) {
        int rm = bm + wr * 32 + fm * 16 + (l >> 4) * 4 + j;
        C[(size_t)rm * ldc + cn] = __expf((acc[fm][fn][j] + bv) * 2.0f);
      }
    }
}

// ---------------------------------------------------------------------------
// dispatch 2: fused score + softmax. 256 blocks XCD-swizzled so each batch's
// 32 blocks land on ONE XCD (kpE[b] = 512KB -> L2-resident). Block = 4 q rows
// x full 512 k (512 threads; lane owns k = t).
// score'[q,k] = -sum_a 2 v_a / (1 + eq[q][a]*ek[a][k]) (softmax-equivalent).
// P fp16: masked q -> uniform 1/512; k>=klen -> exact 0. Garbage reads from
// skipped proj tiles are masked before use (0xAA = -3e-13, no NaN path).
// ---------------------------------------------------------------------------
__global__ __launch_bounds__(512) void score_softmax(
    const float* __restrict__ qpE,    // [B*128][256] = exp(2(qp+b))
    const float* __restrict__ kpE,    // [B][256][512] = exp(2kp)
    const float* __restrict__ v,      // [256]
    const int* __restrict__ qlen_p, const int* __restrict__ klen_p,
    u16* __restrict__ P)              // [B][128][512] fp16
{
  const int p = blockIdx.x;
  const int log = (p & 7) * 32 + (p >> 3);      // batch b entirely on XCD p&7
  const int b = log >> 5, q0 = (log & 31) * 4;
  const int t = threadIdx.x;
  const int qlen = qlen_p[b], klen = klen_p[b];
  const int w = t >> 6, l = t & 63;
  const int k = t;                    // 0..511
  u16* Pb = P + (size_t)(b * 128 + q0) * 512;

  if (q0 >= qlen) {                   // all 4 rows masked -> uniform 1/512
    const u16 uh = f2fh(1.0f / 512.0f);
#pragma unroll
    for (int r = 0; r < 4; r++) Pb[(size_t)r * 512 + k] = uh;
    return;
  }

  __shared__ float sEq[256][4];       // [a][row], uniform-broadcast reads
  __shared__ float sV2[256];
  __shared__ float sRed[8][8];        // [wave][r:max 0..3, r:sum 4..7]

  {
    int a = t & 255, rr = t >> 8;     // rr = 0,1
    sEq[a][rr]     = qpE[(size_t)(b * 128 + q0 + rr) * 256 + a];
    sEq[a][rr + 2] = qpE[(size_t)(b * 128 + q0 + rr + 2) * 256 + a];
    if (t < 256) sV2[t] = 2.0f * v[t];
  }
  __syncthreads();

  // ---- score ----
  float s[4] = {0.f, 0.f, 0.f, 0.f};
  if (w * 64 < klen) {                // wave has at least one active k
    const float* kc = kpE + (size_t)b * 256 * 512 + k;
#pragma unroll 8
    for (int a = 0; a < 256; a++) {
      float ek = kc[(size_t)a * 512];
      f32x4 eq = *(const f32x4*)&sEq[a][0];
      float vv = sV2[a];
#pragma unroll
      for (int r = 0; r < 4; r++)
        s[r] = fmaf(-vv, __builtin_amdgcn_rcpf(fmaf(eq[r], ek, 1.0f)), s[r]);
    }
  }
  if (k >= klen) {
#pragma unroll
    for (int r = 0; r < 4; r++) s[r] = NEGV;
  }

  // ---- softmax over 512 lanes (wave shuffle + 8-wave LDS combine) ----
#pragma unroll
  for (int r = 0; r < 4; r++) {
    float x = s[r];
#pragma unroll
    for (int off = 32; off > 0; off >>= 1) x = fmaxf(x, __shfl_xor(x, off));
    if (l == 0) sRed[w][r] = x;
  }
  __syncthreads();
  float e[4];
#pragma unroll
  for (int r = 0; r < 4; r++) {
    float mm = fmaxf(fmaxf(sRed[0][r], sRed[1][r]),
                     fmaxf(sRed[2][r], sRed[3][r]));
    mm = fmaxf(mm, fmaxf(fmaxf(sRed[4][r], sRed[5][r]),
                         fmaxf(sRed[6][r], sRed[7][r])));
    e[r] = __expf(s[r] - mm);         // k>=klen -> exact 0
  }
  __syncthreads();                    // sRed reuse
#pragma unroll
  for (int r = 0; r < 4; r++) {
    float x = e[r];
#pragma unroll
    for (int off = 32; off > 0; off >>= 1) x += __shfl_xor(x, off);
    if (l == 0) sRed[w][4 + r] = x;
  }
  __syncthreads();

  const u16 uh = f2fh(1.0f / 512.0f);
#pragma unroll
  for (int r = 0; r < 4; r++) {
    float S = (sRed[0][4 + r] + sRed[1][4 + r]) +
              (sRed[2][4 + r] + sRed[3][4 + r]) +
              (sRed[4][4 + r] + sRed[5][4 + r]) +
              (sRed[6][4 + r] + sRed[7][4 + r]);
    float pp = e[r] * __fdividef(1.0f, S);
    Pb[(size_t)r * 512 + k] = (q0 + r < qlen) ? f2fh(pp) : uh;
  }
}

// ---------------------------------------------------------------------------
// dispatch 3: pv. out[b] = P[b](fp16) @ kv[b](f32). 128 blocks XCD-swizzled:
// exactly one batch per XCD (kv[b]+P[b] L2-resident). kv tile transposed to
// [d][k] fp16 in LDS during staging; P staged via global_load_lds.
// ---------------------------------------------------------------------------
__global__ __launch_bounds__(256) void pv_mfma(
    const u16* __restrict__ P, const float* __restrict__ kv,
    float* __restrict__ out)
{
  __shared__ __align__(16) u16 sA[8 * 512];
  __shared__ __align__(16) u16 sB[8 * 512];
  const int p = blockIdx.x;
  const int log = (p & 7) * 16 + (p >> 3);      // one batch per XCD
  const int t = threadIdx.x;
  const int b = log >> 4, r = log & 15;
  const int bm = (r >> 3) * 64, bn = (r & 7) * 64;

  const u16* Ab = P + (size_t)b * 128 * 512;
  const float* Bb = kv + (size_t)b * 512 * 512;

  const int l = t & 63, w = t >> 6;
  const int wr = w >> 1, wc = w & 1;
  const int srow = l >> 3, scol = ((l & 7) ^ srow) << 3;

  const int dq = t & 15, kq = t >> 4;

  float4 v0, v1, v2, v3;
  auto LOADB = [&](int k0) {
    const float* pp = Bb + (size_t)(k0 + kq * 4) * 512 + bn + dq * 4;
    v0 = *(const float4*)pp;
    v1 = *(const float4*)(pp + 512);
    v2 = *(const float4*)(pp + 1024);
    v3 = *(const float4*)(pp + 1536);
  };
  auto WRITEB = [&]() {
#define WRB(jj, ee)                                                       \
    { int d = dq * 4 + jj;                                                \
      f16x4 c; c[0] = (_Float16)v0.ee; c[1] = (_Float16)v1.ee;            \
      c[2] = (_Float16)v2.ee; c[3] = (_Float16)v3.ee;                     \
      *(f16x4*)((char*)sB + d * 128 +                                     \
                ((((kq >> 1) * 16) ^ ((d & 7) << 4)) + (kq & 1) * 8)) = c; }
    WRB(0, x) WRB(1, y) WRB(2, z) WRB(3, w)
#undef WRB
  };

  f32x4 acc[2][2] = {};
  LOADB(0);
  for (int k0 = 0; k0 < 512; k0 += 64) {
    __syncthreads();
    WRITEB();
#pragma unroll
    for (int i = 0; i < 2; i++) {
      int s = w * 2 + i;
      gload16(Ab + (size_t)(bm + s * 8 + srow) * 512 + k0 + scol, sA + s * 512);
    }
    if (k0 + 64 < 512) LOADB(k0 + 64);
    __syncthreads();
    mfma_tile(sA, sB, l, wr, wc, acc);
  }

  float* Cb = out + (size_t)b * 128 * 512;
#pragma unroll
  for (int fm = 0; fm < 2; fm++)
#pragma unroll
    for (int fn = 0; fn < 2; fn++) {
      int cn = bn + wc * 32 + fn * 16 + (l & 15);
#pragma unroll
      for (int j = 0; j < 4; j++) {
        int rm = bm + wr * 32 + fm * 16 + (l >> 4) * 4 + j;
        Cb[(size_t)rm * 512 + cn] = acc[fm][fn][j];
      }
    }
}

// ---------------------------------------------------------------------------
extern "C" void kernel_launch(void* const* d_in, const int* in_sizes, int n_in,
                              void* d_out, int out_size, void* d_ws, size_t ws_size,
                              hipStream_t stream)
{
  const float* query = (const float*)d_in[0];  // [8][128][512]
  const float* kv    = (const float*)d_in[1];  // [8][512][512]
  const float* W     = (const float*)d_in[2];  // [256][1024]
  const float* bbias = (const float*)d_in[3];  // [256]
  const float* v     = (const float*)d_in[4];  // [256]
  const int*   qlen  = (const int*)d_in[5];    // [8]
  const int*   klen  = (const int*)d_in[6];    // [8]
  float* out = (float*)d_out;                  // [8][128][512]

  float* qpE = (float*)d_ws;                   // 1MB
  float* kpE = qpE + 1024 * 256;               // 4MB
  u16*   P   = (u16*)(kpE + 8 * 256 * 512);    // 1MB

  proj_mfma<<<dim3(320), 256, 0, stream>>>(
      query, kv, W, bbias, qlen, klen, qpE, kpE);

  score_softmax<<<dim3(256), 512, 0, stream>>>(
      qpE, kpE, v, qlen, klen, P);

  pv_mfma<<<dim3(128), 256, 0, stream>>>(P, kv, out);
}